// Round 1
// baseline (197.997 us; speedup 1.0000x reference)
//
#include <hip/hip_runtime.h>
#include <stdint.h>

#define NUM_CLASSES 16
#define HW (512 * 512)            // 262144 = 2^18
#define NPIX (8 * HW)             // 2,097,152 pixels
#define NVEC (NPIX / 4)           // 524,288 float4-groups
#define HIST_BINS (NUM_CLASSES * NUM_CLASSES)  // 256

// Kernel 1: per-pixel argmax over 16 class planes + joint (pred,target)
// histogram. Memory-bound: 16 coalesced float4 streams (one per class plane)
// + 1 int4 target stream. 1 LDS atomic per pixel (joint hist), one global
// atomic flush per block per bin.
__global__ __launch_bounds__(256) void jaccard_hist_kernel(
    const float* __restrict__ pred,
    const int* __restrict__ target,
    unsigned int* __restrict__ ghist) {
  __shared__ unsigned int lh[HIST_BINS];
  lh[threadIdx.x] = 0u;  // 256 threads cover 256 bins
  __syncthreads();

  int tid = blockIdx.x * blockDim.x + threadIdx.x;
  int stride = gridDim.x * blockDim.x;

  for (int i = tid; i < NVEC; i += stride) {
    int idx4 = i << 2;                 // first pixel of this group
    int b = idx4 >> 18;                // batch index (HW = 2^18)
    int hw = idx4 & (HW - 1);          // offset within plane, multiple of 4
    const float* base = pred + (size_t)b * NUM_CLASSES * HW + hw;

    float4 best = *(const float4*)(base);
    int ax = 0, ay = 0, az = 0, aw = 0;
#pragma unroll
    for (int c = 1; c < NUM_CLASSES; ++c) {
      float4 v = *(const float4*)(base + (size_t)c * HW);
      // strict > keeps first occurrence of the max (jnp.argmax semantics)
      if (v.x > best.x) { best.x = v.x; ax = c; }
      if (v.y > best.y) { best.y = v.y; ay = c; }
      if (v.z > best.z) { best.z = v.z; az = c; }
      if (v.w > best.w) { best.w = v.w; aw = c; }
    }

    int4 t = *(const int4*)(target + idx4);
    atomicAdd(&lh[(ax << 4) + t.x], 1u);
    atomicAdd(&lh[(ay << 4) + t.y], 1u);
    atomicAdd(&lh[(az << 4) + t.z], 1u);
    atomicAdd(&lh[(aw << 4) + t.w], 1u);
  }

  __syncthreads();
  unsigned int v = lh[threadIdx.x];
  if (v) atomicAdd(&ghist[threadIdx.x], v);
}

// Kernel 2: one wave. counts_p[c] = row sum, counts_t[c] = col sum,
// inter[c] = diagonal; score = inter/union (1.0 if union==0); out = mean.
__global__ __launch_bounds__(64) void jaccard_finalize_kernel(
    const unsigned int* __restrict__ ghist, float* __restrict__ out) {
  __shared__ unsigned int h[HIST_BINS];
  int l = threadIdx.x;  // 0..63
#pragma unroll
  for (int k = 0; k < 4; ++k) h[l + 64 * k] = ghist[l + 64 * k];
  __syncthreads();

  float score = 0.0f;
  if (l < NUM_CLASSES) {
    unsigned int cp = 0, ct = 0;
#pragma unroll
    for (int j = 0; j < NUM_CLASSES; ++j) {
      cp += h[l * 16 + j];   // pred == l
      ct += h[j * 16 + l];   // target == l
    }
    unsigned int inter = h[l * 17];  // pred == target == l
    float uni = (float)cp + (float)ct - (float)inter;
    score = (uni == 0.0f) ? 1.0f : ((float)inter / uni);
  }

  // reduce 16 partial scores living in lanes 0..15 (lanes 16..63 are 0)
#pragma unroll
  for (int off = 8; off >= 1; off >>= 1) score += __shfl_down(score, off, 64);

  if (l == 0) out[0] = score * (1.0f / (float)NUM_CLASSES);
}

extern "C" void kernel_launch(void* const* d_in, const int* in_sizes, int n_in,
                              void* d_out, int out_size, void* d_ws, size_t ws_size,
                              hipStream_t stream) {
  const float* pred = (const float*)d_in[0];
  const int* target = (const int*)d_in[1];
  float* out = (float*)d_out;
  unsigned int* ghist = (unsigned int*)d_ws;

  // d_ws is re-poisoned to 0xAA before every timed call — zero it each time.
  hipMemsetAsync(d_ws, 0, HIST_BINS * sizeof(unsigned int), stream);

  // 512 blocks x 256 threads, 4 grid-stride iterations/thread, exact coverage.
  jaccard_hist_kernel<<<512, 256, 0, stream>>>(pred, target, ghist);
  jaccard_finalize_kernel<<<1, 64, 0, stream>>>(ghist, out);
}